// Round 3
// baseline (156.377 us; speedup 1.0000x reference)
//
#include <hip/hip_runtime.h>
#include <hip/hip_bf16.h>
#include <stdint.h>

// TopKPooling (haiku-geometric): N=200000, C=256, B=64, E=3.2M, RATIO=0.5
// Inputs (f32/int32): x [N,C] f32, p [C] f32, senders/receivers int32, batch int32 (sorted).
// Output d_out: FLOAT32, concatenated (x_out [N*C] | senders_out [E] | receivers_out [E]
// | new_batch_sorted [N]).

#define RATIO 0.5f

// Kernel 1: score[i] = dot(x[i,:], p). One 64-lane wave per node, float4 per lane (C=256).
__global__ __launch_bounds__(256) void k_scores(
    const float* __restrict__ x, const float* __restrict__ p,
    float* __restrict__ s, int N) {
    int node = blockIdx.x * 4 + (threadIdx.x >> 6);
    int lane = threadIdx.x & 63;
    if (node >= N) return;
    const float4 pv = *reinterpret_cast<const float4*>(p + lane * 4);
    const float4 xv = *reinterpret_cast<const float4*>(x + (size_t)node * 256 + lane * 4);
    float acc = xv.x * pv.x + xv.y * pv.y + xv.z * pv.z + xv.w * pv.w;
    #pragma unroll
    for (int off = 32; off; off >>= 1) acc += __shfl_down(acc, off, 64);
    if (lane == 0) s[node] = acc;
}

// Kernel 2: segment starts from sorted batch.
__global__ __launch_bounds__(256) void k_boundary(
    const int* __restrict__ batch, int N, int* __restrict__ start) {
    int i = blockIdx.x * blockDim.x + threadIdx.x;
    if (i >= N) return;
    int b = batch[i];
    if (i == 0 || batch[i - 1] != b) start[b] = i;
}

// Kernel 3: per-graph counts, k = ceil(RATIO*cnt), exclusive prefix sums. One wave.
__global__ __launch_bounds__(64) void k_meta(
    int N, int B, const int* __restrict__ start,
    int* __restrict__ kk, int* __restrict__ Kb, int* __restrict__ Db,
    int* __restrict__ Ktot) {
    int g = threadIdx.x;             // 0..63 == B lanes
    int st = start[g];
    int en = (g == B - 1) ? N : start[g + 1];
    int cnt = en - st;
    int kv = (int)ceilf(RATIO * (float)cnt);
    int dv = cnt - kv;
    int kp = kv, dp = dv;
    #pragma unroll
    for (int off = 1; off < 64; off <<= 1) {
        int a = __shfl_up(kp, off, 64);
        int b_ = __shfl_up(dp, off, 64);
        if (g >= off) { kp += a; dp += b_; }
    }
    kk[g] = kv;
    Kb[g] = kp - kv;   // exclusive prefix of kept counts
    Db[g] = dp - dv;   // exclusive prefix of dropped counts
    if (g == B - 1) *Ktot = kp;
}

// Kernel 4: per-graph softmax stats (max, sum of exp).
__global__ __launch_bounds__(256) void k_stats(
    const float* __restrict__ s, const int* __restrict__ start, int N, int B,
    float* __restrict__ mx, float* __restrict__ denom) {
    int g = blockIdx.x;
    int st = start[g];
    int en = (g == B - 1) ? N : start[g + 1];
    __shared__ float red[256];
    float m = -INFINITY;
    for (int i = st + threadIdx.x; i < en; i += 256) m = fmaxf(m, s[i]);
    red[threadIdx.x] = m; __syncthreads();
    for (int o = 128; o; o >>= 1) {
        if (threadIdx.x < o) red[threadIdx.x] = fmaxf(red[threadIdx.x], red[threadIdx.x + o]);
        __syncthreads();
    }
    m = red[0]; __syncthreads();
    float sum = 0.f;
    for (int i = st + threadIdx.x; i < en; i += 256) sum += expf(s[i] - m);
    red[threadIdx.x] = sum; __syncthreads();
    for (int o = 128; o; o >>= 1) {
        if (threadIdx.x < o) red[threadIdx.x] += red[threadIdx.x + o];
        __syncthreads();
    }
    if (threadIdx.x == 0) { mx[g] = m; denom[g] = red[0]; }
}

// Kernel 5: gate rows by softmax score, scatter to sorted position, emit new_batch_sorted.
// Stable argsort of new_batch => kept node (graph g, segment idx) -> Kb[g]+idx;
// dropped -> Ktot + Db[g] + (idx - k[g]).
__global__ __launch_bounds__(256) void k_scatter(
    const float* __restrict__ x, const float* __restrict__ s,
    const int* __restrict__ batch, const int* __restrict__ start,
    const int* __restrict__ kk, const int* __restrict__ Kb, const int* __restrict__ Db,
    const int* __restrict__ Ktot, const float* __restrict__ mx, const float* __restrict__ denom,
    int N, int B, float* __restrict__ xout, float* __restrict__ nbout) {
    int node = blockIdx.x * 4 + (threadIdx.x >> 6);
    if (node >= N) return;
    int lane = threadIdx.x & 63;
    int g = batch[node];
    int idx = node - start[g];
    int kv = kk[g];
    bool kept = idx < kv;
    int pos = kept ? (Kb[g] + idx) : (*Ktot + Db[g] + (idx - kv));
    float sc = expf(s[node] - mx[g]) / denom[g];
    const float4 xv = *reinterpret_cast<const float4*>(x + (size_t)node * 256 + lane * 4);
    float4 o;
    o.x = xv.x * sc;
    o.y = xv.y * sc;
    o.z = xv.z * sc;
    o.w = xv.w * sc;
    *reinterpret_cast<float4*>(xout + (size_t)pos * 256 + lane * 4) = o;
    if (lane == 0) nbout[pos] = (float)(kept ? g : B);
}

// Kernel 6: edge rewrite. new_batch_sorted[id]==B <=> id >= Ktot (reference indexes the
// sorted batch array with ORIGINAL ids — faithful). senders_out = mask ? recv : send;
// receivers_out = recv (the sequential where-overwrite always yields receivers).
__global__ __launch_bounds__(256) void k_edges(
    const int* __restrict__ snd, const int* __restrict__ rcv, int E,
    const int* __restrict__ Ktot,
    float* __restrict__ sout, float* __restrict__ rout) {
    int t = blockIdx.x * blockDim.x + threadIdx.x;
    int base = t * 4;
    if (base >= E) return;
    int kt = *Ktot;
    if (base + 4 <= E) {
        int4 s4 = *reinterpret_cast<const int4*>(snd + base);
        int4 r4 = *reinterpret_cast<const int4*>(rcv + base);
        float4 so, ro;
        so.x = (float)(((s4.x >= kt) || (r4.x >= kt)) ? r4.x : s4.x);
        so.y = (float)(((s4.y >= kt) || (r4.y >= kt)) ? r4.y : s4.y);
        so.z = (float)(((s4.z >= kt) || (r4.z >= kt)) ? r4.z : s4.z);
        so.w = (float)(((s4.w >= kt) || (r4.w >= kt)) ? r4.w : s4.w);
        ro.x = (float)r4.x;
        ro.y = (float)r4.y;
        ro.z = (float)r4.z;
        ro.w = (float)r4.w;
        *reinterpret_cast<float4*>(sout + base) = so;
        *reinterpret_cast<float4*>(rout + base) = ro;
    } else {
        for (int e = base; e < E; ++e) {
            int sv = snd[e], rv = rcv[e];
            bool m = (sv >= kt) || (rv >= kt);
            sout[e] = (float)(m ? rv : sv);
            rout[e] = (float)rv;
        }
    }
}

extern "C" void kernel_launch(void* const* d_in, const int* in_sizes, int n_in,
                              void* d_out, int out_size, void* d_ws, size_t ws_size,
                              hipStream_t stream) {
    const float* x = (const float*)d_in[0];
    const float* p = (const float*)d_in[1];
    const int* senders = (const int*)d_in[2];
    const int* receivers = (const int*)d_in[3];
    const int* batch = (const int*)d_in[4];

    const int C = in_sizes[1];   // 256
    const int E = in_sizes[2];   // 3,200,000
    const int N = in_sizes[4];   // 200,000
    const int B = 64;

    char* ws = (char*)d_ws;
    float* s   = (float*)ws;                       // N floats
    int* start = (int*)(ws + (size_t)N * 4);       // B ints
    int* kk    = start + B;
    int* Kb    = kk + B;
    int* Db    = Kb + B;
    int* Ktot  = Db + B;
    float* mx    = (float*)(Ktot + 1);
    float* denom = mx + B;

    float* out   = (float*)d_out;
    float* xout  = out;
    float* sout  = out + (size_t)N * C;
    float* rout  = sout + E;
    float* nbout = rout + E;

    k_scores  <<<(N + 3) / 4, 256, 0, stream>>>(x, p, s, N);
    k_boundary<<<(N + 255) / 256, 256, 0, stream>>>(batch, N, start);
    k_meta    <<<1, 64, 0, stream>>>(N, B, start, kk, Kb, Db, Ktot);
    k_stats   <<<B, 256, 0, stream>>>(s, start, N, B, mx, denom);
    k_scatter <<<(N + 3) / 4, 256, 0, stream>>>(x, s, batch, start, kk, Kb, Db, Ktot,
                                                mx, denom, N, B, xout, nbout);
    k_edges   <<<(E + 1023) / 1024, 256, 0, stream>>>(senders, receivers, E, Ktot, sout, rout);
}

// Round 4
// 125.903 us; speedup vs baseline: 1.2420x; 1.2420x over previous
//
#include <hip/hip_runtime.h>
#include <hip/hip_bf16.h>
#include <stdint.h>

// TopKPooling (haiku-geometric): N=200000, C=256, B=64, E=3.2M, RATIO=0.5
// Inputs (f32/int32): x [N,C] f32, p [C] f32, senders/receivers int32, batch int32 (sorted).
// Output d_out: FLOAT32, concatenated (x_out [N*C] | senders_out [E] | receivers_out [E]
// | new_batch_sorted [N]).
//
// R4: non-temporal stores for all outputs + nt loads for edge arrays, so the
// xout/sout/rout write streams don't evict x from Infinity Cache between
// k_scores (first x read) and k_scatter (second x read).

#define RATIO 0.5f

typedef float f32x4 __attribute__((ext_vector_type(4)));
typedef int   i32x4 __attribute__((ext_vector_type(4)));

// Kernel 1: score[i] = dot(x[i,:], p). One 64-lane wave per node, float4 per lane (C=256).
__global__ __launch_bounds__(256) void k_scores(
    const float* __restrict__ x, const float* __restrict__ p,
    float* __restrict__ s, int N) {
    int node = blockIdx.x * 4 + (threadIdx.x >> 6);
    int lane = threadIdx.x & 63;
    if (node >= N) return;
    const f32x4 pv = *reinterpret_cast<const f32x4*>(p + lane * 4);
    const f32x4 xv = *reinterpret_cast<const f32x4*>(x + (size_t)node * 256 + lane * 4);
    float acc = xv.x * pv.x + xv.y * pv.y + xv.z * pv.z + xv.w * pv.w;
    #pragma unroll
    for (int off = 32; off; off >>= 1) acc += __shfl_down(acc, off, 64);
    if (lane == 0) s[node] = acc;
}

// Kernel 2: segment starts from sorted batch.
__global__ __launch_bounds__(256) void k_boundary(
    const int* __restrict__ batch, int N, int* __restrict__ start) {
    int i = blockIdx.x * blockDim.x + threadIdx.x;
    if (i >= N) return;
    int b = batch[i];
    if (i == 0 || batch[i - 1] != b) start[b] = i;
}

// Kernel 3: per-graph counts, k = ceil(RATIO*cnt), exclusive prefix sums. One wave.
__global__ __launch_bounds__(64) void k_meta(
    int N, int B, const int* __restrict__ start,
    int* __restrict__ kk, int* __restrict__ Kb, int* __restrict__ Db,
    int* __restrict__ Ktot) {
    int g = threadIdx.x;             // 0..63 == B lanes
    int st = start[g];
    int en = (g == B - 1) ? N : start[g + 1];
    int cnt = en - st;
    int kv = (int)ceilf(RATIO * (float)cnt);
    int dv = cnt - kv;
    int kp = kv, dp = dv;
    #pragma unroll
    for (int off = 1; off < 64; off <<= 1) {
        int a = __shfl_up(kp, off, 64);
        int b_ = __shfl_up(dp, off, 64);
        if (g >= off) { kp += a; dp += b_; }
    }
    kk[g] = kv;
    Kb[g] = kp - kv;   // exclusive prefix of kept counts
    Db[g] = dp - dv;   // exclusive prefix of dropped counts
    if (g == B - 1) *Ktot = kp;
}

// Kernel 4: per-graph softmax stats (max, sum of exp).
__global__ __launch_bounds__(256) void k_stats(
    const float* __restrict__ s, const int* __restrict__ start, int N, int B,
    float* __restrict__ mx, float* __restrict__ denom) {
    int g = blockIdx.x;
    int st = start[g];
    int en = (g == B - 1) ? N : start[g + 1];
    __shared__ float red[256];
    float m = -INFINITY;
    for (int i = st + threadIdx.x; i < en; i += 256) m = fmaxf(m, s[i]);
    red[threadIdx.x] = m; __syncthreads();
    for (int o = 128; o; o >>= 1) {
        if (threadIdx.x < o) red[threadIdx.x] = fmaxf(red[threadIdx.x], red[threadIdx.x + o]);
        __syncthreads();
    }
    m = red[0]; __syncthreads();
    float sum = 0.f;
    for (int i = st + threadIdx.x; i < en; i += 256) sum += expf(s[i] - m);
    red[threadIdx.x] = sum; __syncthreads();
    for (int o = 128; o; o >>= 1) {
        if (threadIdx.x < o) red[threadIdx.x] += red[threadIdx.x + o];
        __syncthreads();
    }
    if (threadIdx.x == 0) { mx[g] = m; denom[g] = red[0]; }
}

// Kernel 5: gate rows by softmax score, scatter to sorted position, emit new_batch_sorted.
// Stable argsort of new_batch => kept node (graph g, segment idx) -> Kb[g]+idx;
// dropped -> Ktot + Db[g] + (idx - k[g]).  Output stores are non-temporal so the
// write stream doesn't evict x (L3-resident from k_scores).
__global__ __launch_bounds__(256) void k_scatter(
    const float* __restrict__ x, const float* __restrict__ s,
    const int* __restrict__ batch, const int* __restrict__ start,
    const int* __restrict__ kk, const int* __restrict__ Kb, const int* __restrict__ Db,
    const int* __restrict__ Ktot, const float* __restrict__ mx, const float* __restrict__ denom,
    int N, int B, float* __restrict__ xout, float* __restrict__ nbout) {
    int node = blockIdx.x * 4 + (threadIdx.x >> 6);
    if (node >= N) return;
    int lane = threadIdx.x & 63;
    int g = batch[node];
    int idx = node - start[g];
    int kv = kk[g];
    bool kept = idx < kv;
    int pos = kept ? (Kb[g] + idx) : (*Ktot + Db[g] + (idx - kv));
    float sc = expf(s[node] - mx[g]) / denom[g];
    const f32x4 xv = *reinterpret_cast<const f32x4*>(x + (size_t)node * 256 + lane * 4);
    f32x4 o;
    o.x = xv.x * sc;
    o.y = xv.y * sc;
    o.z = xv.z * sc;
    o.w = xv.w * sc;
    __builtin_nontemporal_store(o, reinterpret_cast<f32x4*>(xout + (size_t)pos * 256 + lane * 4));
    if (lane == 0)
        __builtin_nontemporal_store((float)(kept ? g : B), nbout + pos);
}

// Kernel 6: edge rewrite. new_batch_sorted[id]==B <=> id >= Ktot.
// senders_out = mask ? recv : send; receivers_out = recv (sequential where-overwrite).
// Single-use streams: nt loads + nt stores.
__global__ __launch_bounds__(256) void k_edges(
    const int* __restrict__ snd, const int* __restrict__ rcv, int E,
    const int* __restrict__ Ktot,
    float* __restrict__ sout, float* __restrict__ rout) {
    int t = blockIdx.x * blockDim.x + threadIdx.x;
    int base = t * 4;
    if (base >= E) return;
    int kt = *Ktot;
    if (base + 4 <= E) {
        i32x4 s4 = __builtin_nontemporal_load(reinterpret_cast<const i32x4*>(snd + base));
        i32x4 r4 = __builtin_nontemporal_load(reinterpret_cast<const i32x4*>(rcv + base));
        f32x4 so, ro;
        so.x = (float)(((s4.x >= kt) || (r4.x >= kt)) ? r4.x : s4.x);
        so.y = (float)(((s4.y >= kt) || (r4.y >= kt)) ? r4.y : s4.y);
        so.z = (float)(((s4.z >= kt) || (r4.z >= kt)) ? r4.z : s4.z);
        so.w = (float)(((s4.w >= kt) || (r4.w >= kt)) ? r4.w : s4.w);
        ro.x = (float)r4.x;
        ro.y = (float)r4.y;
        ro.z = (float)r4.z;
        ro.w = (float)r4.w;
        __builtin_nontemporal_store(so, reinterpret_cast<f32x4*>(sout + base));
        __builtin_nontemporal_store(ro, reinterpret_cast<f32x4*>(rout + base));
    } else {
        for (int e = base; e < E; ++e) {
            int sv = snd[e], rv = rcv[e];
            bool m = (sv >= kt) || (rv >= kt);
            sout[e] = (float)(m ? rv : sv);
            rout[e] = (float)rv;
        }
    }
}

extern "C" void kernel_launch(void* const* d_in, const int* in_sizes, int n_in,
                              void* d_out, int out_size, void* d_ws, size_t ws_size,
                              hipStream_t stream) {
    const float* x = (const float*)d_in[0];
    const float* p = (const float*)d_in[1];
    const int* senders = (const int*)d_in[2];
    const int* receivers = (const int*)d_in[3];
    const int* batch = (const int*)d_in[4];

    const int C = in_sizes[1];   // 256
    const int E = in_sizes[2];   // 3,200,000
    const int N = in_sizes[4];   // 200,000
    const int B = 64;

    char* ws = (char*)d_ws;
    float* s   = (float*)ws;                       // N floats
    int* start = (int*)(ws + (size_t)N * 4);       // B ints
    int* kk    = start + B;
    int* Kb    = kk + B;
    int* Db    = Kb + B;
    int* Ktot  = Db + B;
    float* mx    = (float*)(Ktot + 1);
    float* denom = mx + B;

    float* out   = (float*)d_out;
    float* xout  = out;
    float* sout  = out + (size_t)N * C;
    float* rout  = sout + E;
    float* nbout = rout + E;

    k_scores  <<<(N + 3) / 4, 256, 0, stream>>>(x, p, s, N);
    k_boundary<<<(N + 255) / 256, 256, 0, stream>>>(batch, N, start);
    k_meta    <<<1, 64, 0, stream>>>(N, B, start, kk, Kb, Db, Ktot);
    k_stats   <<<B, 256, 0, stream>>>(s, start, N, B, mx, denom);
    k_scatter <<<(N + 3) / 4, 256, 0, stream>>>(x, s, batch, start, kk, Kb, Db, Ktot,
                                                mx, denom, N, B, xout, nbout);
    k_edges   <<<(E + 1023) / 1024, 256, 0, stream>>>(senders, receivers, E, Ktot, sout, rout);
}